// Round 1
// baseline (156.202 us; speedup 1.0000x reference)
//
#include <hip/hip_runtime.h>
#include <hip/hip_bf16.h>
#include <cstdint>
#include <cstddef>

// ---------------------------------------------------------------------------
// Biaffine: out[b,x,y,o] = sum_ij in1[b,x,i] w1[i,o,j] in2[b,y,j]
//                        + in1[b,x,:]@w2[:D] + in2[b,y,:]@w2[D:2D] + w2[2D]
// B=32 S=1024 D=256 O=2.  Factored:
//   stage1: T[bx, oj] = in1b[bx,:] @ w1t[oj,:]^T      (GEMM 32768x512x256)
//   stage2: out[b,x,y,o] = T[bx, o*256+:] . in2b[by,:] (+ lin epilogue)
// ---------------------------------------------------------------------------

typedef __bf16 bf16_t;
typedef __bf16 bf16x4 __attribute__((ext_vector_type(4)));
typedef __bf16 bf16x8 __attribute__((ext_vector_type(8)));
typedef float  f32x4  __attribute__((ext_vector_type(4)));

#define NB   32
#define NS   1024
#define ND   256
#define NM   (NB * NS)      // 32768 rows of input1/input2
#define NN1  512            // O*D columns of T

__device__ __forceinline__ void gload_lds16(const void* g, void* l) {
  __builtin_amdgcn_global_load_lds(
      (__attribute__((address_space(1))) void*)g,
      (__attribute__((address_space(3))) void*)l, 16, 0, 0);
}

// ---------------------------------------------------------------------------
// prep: cast in1/in2 -> bf16, compute lin1/lin2 (+bias into lin2),
//       transpose+cast w1 -> w1t[oj][i]
// grid: 16384 row-blocks (4 rows each, one wave per row) + 64 w1t blocks
// ---------------------------------------------------------------------------
__global__ __launch_bounds__(256) void prep_kernel(
    const float* __restrict__ in1, const float* __restrict__ in2,
    const float* __restrict__ w1,  const float* __restrict__ w2,
    bf16_t* __restrict__ in1b, bf16_t* __restrict__ in2b,
    bf16_t* __restrict__ w1t,  float* __restrict__ lin)
{
  int bid = blockIdx.x;
  if (bid < 16384) {
    int wave = threadIdx.x >> 6;
    int lane = threadIdx.x & 63;
    int r  = bid * 4 + wave;          // 0..65535
    int is2 = (r >= NM) ? 1 : 0;
    int lr = r & (NM - 1);
    const float* src = is2 ? in2 : in1;
    bf16_t*      dst = is2 ? in2b : in1b;

    float4 v = *(const float4*)(src + (size_t)lr * ND + lane * 4);
    bf16x4 h;
    h[0] = (bf16_t)v.x; h[1] = (bf16_t)v.y; h[2] = (bf16_t)v.z; h[3] = (bf16_t)v.w;
    *(bf16x4*)(dst + (size_t)lr * ND + lane * 4) = h;

    // linear-term partial: d = lane*4 + k; w2 row = d (in1) or D+d (in2)
    int dbase = is2 * ND + lane * 4;
    float a0 = v.x * w2[(dbase + 0) * 2 + 0] + v.y * w2[(dbase + 1) * 2 + 0]
             + v.z * w2[(dbase + 2) * 2 + 0] + v.w * w2[(dbase + 3) * 2 + 0];
    float a1 = v.x * w2[(dbase + 0) * 2 + 1] + v.y * w2[(dbase + 1) * 2 + 1]
             + v.z * w2[(dbase + 2) * 2 + 1] + v.w * w2[(dbase + 3) * 2 + 1];
    #pragma unroll
    for (int off = 32; off > 0; off >>= 1) {
      a0 += __shfl_down(a0, off, 64);
      a1 += __shfl_down(a1, off, 64);
    }
    if (lane == 0) {
      if (is2) { a0 += w2[2 * ND * 2 + 0]; a1 += w2[2 * ND * 2 + 1]; } // bias
      lin[r * 2 + 0] = a0;
      lin[r * 2 + 1] = a1;
    }
  } else {
    // w1t[oj*256 + i] = w1[i*512 + oj]
    int wb = bid - 16384;             // 0..63
    int t  = threadIdx.x;
    #pragma unroll
    for (int e = 0; e < 8; ++e) {
      int q  = wb * 2048 + e * 256 + t;   // 0..131071
      int oj = q >> 8;
      int i  = q & 255;
      w1t[q] = (bf16_t)w1[i * NN1 + oj];
    }
  }
}

// ---------------------------------------------------------------------------
// gemm1: T[m, n] = sum_k A[m,k] * Bt[n,k]
//   A = in1b (32768 x 256, row-major), Bt = w1t (512 x 256, row-major)
// 128x128 tile, BK=64, 4 waves (2x2), each wave 64x64 of 16x16x32 MFMA
// ---------------------------------------------------------------------------
__global__ __launch_bounds__(256) void gemm1_kernel(
    const bf16_t* __restrict__ A, const bf16_t* __restrict__ Bt,
    bf16_t* __restrict__ T)
{
  __shared__ bf16_t As[128 * 64];
  __shared__ bf16_t Bs[128 * 64];

  int m0 = blockIdx.y * 128;
  int n0 = blockIdx.x * 128;
  int t = threadIdx.x;
  int wid = t >> 6, lane = t & 63;
  int wm = (wid >> 1) * 64, wn = (wid & 1) * 64;

  f32x4 acc[4][4] = {};

  int srow = t >> 3;            // 0..31 staging row
  int sce  = (t & 7) * 8;       // element offset in 64-wide row

  for (int kt = 0; kt < 4; ++kt) {
    int k0 = kt * 64;
    #pragma unroll
    for (int i = 0; i < 4; ++i) {
      int row = srow + i * 32;
      gload_lds16(A  + (size_t)(m0 + row) * ND + k0 + sce, &As[row * 64 + sce]);
      gload_lds16(Bt + (size_t)(n0 + row) * ND + k0 + sce, &Bs[row * 64 + sce]);
    }
    __syncthreads();

    #pragma unroll
    for (int kk = 0; kk < 2; ++kk) {
      int kb = kk * 32 + (lane >> 4) * 8;
      bf16x8 af[4], bfr[4];
      #pragma unroll
      for (int i = 0; i < 4; ++i)
        af[i]  = *(const bf16x8*)&As[(wm + i * 16 + (lane & 15)) * 64 + kb];
      #pragma unroll
      for (int i = 0; i < 4; ++i)
        bfr[i] = *(const bf16x8*)&Bs[(wn + i * 16 + (lane & 15)) * 64 + kb];
      #pragma unroll
      for (int mi = 0; mi < 4; ++mi)
        #pragma unroll
        for (int ni = 0; ni < 4; ++ni)
          acc[mi][ni] = __builtin_amdgcn_mfma_f32_16x16x32_bf16(
              af[mi], bfr[ni], acc[mi][ni], 0, 0, 0);
    }
    __syncthreads();
  }

  // C/D layout: col = lane&15, row = (lane>>4)*4 + r   [m89/m91]
  #pragma unroll
  for (int mi = 0; mi < 4; ++mi) {
    int row = m0 + wm + mi * 16 + ((lane >> 4) << 2);
    #pragma unroll
    for (int ni = 0; ni < 4; ++ni) {
      int col = n0 + wn + ni * 16 + (lane & 15);
      #pragma unroll
      for (int r = 0; r < 4; ++r)
        T[(size_t)(row + r) * NN1 + col] = (bf16_t)acc[mi][ni][r];
    }
  }
}

// ---------------------------------------------------------------------------
// gemm2: per batch b: out[x,y,o] = sum_j T[bx, o*256+j] * in2b[by, j]
//        + lin1[b,x,o] + lin2[b,y,o]   (bias already folded into lin2)
// 128x128 tile, both o per block, BK=64, 4 waves (2x2)
// ---------------------------------------------------------------------------
__global__ __launch_bounds__(256) void gemm2_kernel(
    const bf16_t* __restrict__ T, const bf16_t* __restrict__ in2b,
    const float* __restrict__ lin, float* __restrict__ out)
{
  __shared__ bf16_t As0[128 * 64];
  __shared__ bf16_t As1[128 * 64];
  __shared__ bf16_t Bs[128 * 64];

  int b  = blockIdx.z;
  int x0 = blockIdx.y * 128;
  int y0 = blockIdx.x * 128;
  const bf16_t* Tb = T    + (size_t)b * NS * NN1;
  const bf16_t* Ib = in2b + (size_t)b * NS * ND;

  int t = threadIdx.x;
  int wid = t >> 6, lane = t & 63;
  int wm = (wid >> 1) * 64, wn = (wid & 1) * 64;

  f32x4 acc0[4][4] = {};
  f32x4 acc1[4][4] = {};

  int srow = t >> 3;
  int sce  = (t & 7) * 8;

  for (int kt = 0; kt < 4; ++kt) {
    int k0 = kt * 64;
    #pragma unroll
    for (int i = 0; i < 4; ++i) {
      int row = srow + i * 32;
      gload_lds16(Tb + (size_t)(x0 + row) * NN1 + k0 + sce,       &As0[row * 64 + sce]);
      gload_lds16(Tb + (size_t)(x0 + row) * NN1 + 256 + k0 + sce, &As1[row * 64 + sce]);
      gload_lds16(Ib + (size_t)(y0 + row) * ND + k0 + sce,        &Bs[row * 64 + sce]);
    }
    __syncthreads();

    #pragma unroll
    for (int kk = 0; kk < 2; ++kk) {
      int kb = kk * 32 + (lane >> 4) * 8;
      bf16x8 bfr[4];
      #pragma unroll
      for (int i = 0; i < 4; ++i)
        bfr[i] = *(const bf16x8*)&Bs[(wn + i * 16 + (lane & 15)) * 64 + kb];

      bf16x8 af[4];
      #pragma unroll
      for (int i = 0; i < 4; ++i)
        af[i] = *(const bf16x8*)&As0[(wm + i * 16 + (lane & 15)) * 64 + kb];
      #pragma unroll
      for (int mi = 0; mi < 4; ++mi)
        #pragma unroll
        for (int ni = 0; ni < 4; ++ni)
          acc0[mi][ni] = __builtin_amdgcn_mfma_f32_16x16x32_bf16(
              af[mi], bfr[ni], acc0[mi][ni], 0, 0, 0);

      #pragma unroll
      for (int i = 0; i < 4; ++i)
        af[i] = *(const bf16x8*)&As1[(wm + i * 16 + (lane & 15)) * 64 + kb];
      #pragma unroll
      for (int mi = 0; mi < 4; ++mi)
        #pragma unroll
        for (int ni = 0; ni < 4; ++ni)
          acc1[mi][ni] = __builtin_amdgcn_mfma_f32_16x16x32_bf16(
              af[mi], bfr[ni], acc1[mi][ni], 0, 0, 0);
    }
    __syncthreads();
  }

  // epilogue: out float2 (o=0,1), + lin1[row] + lin2[col]
  float2* outb = (float2*)(out + (size_t)b * NS * NS * 2);
  const float2* l1p = (const float2*)(lin + (size_t)(b * NS) * 2);
  const float2* l2p = (const float2*)(lin + (size_t)(NM + b * NS) * 2);

  #pragma unroll
  for (int mi = 0; mi < 4; ++mi) {
    int rbase = wm + mi * 16 + ((lane >> 4) << 2);   // row within batch-tile
    float2 l1[4];
    #pragma unroll
    for (int r = 0; r < 4; ++r) l1[r] = l1p[x0 + rbase + r];
    #pragma unroll
    for (int ni = 0; ni < 4; ++ni) {
      int col = y0 + wn + ni * 16 + (lane & 15);
      float2 l2 = l2p[col];
      #pragma unroll
      for (int r = 0; r < 4; ++r) {
        int row = x0 + rbase + r;
        float2 v;
        v.x = acc0[mi][ni][r] + l1[r].x + l2.x;
        v.y = acc1[mi][ni][r] + l1[r].y + l2.y;
        outb[(size_t)row * NS + col] = v;
      }
    }
  }
}

// ---------------------------------------------------------------------------
extern "C" void kernel_launch(void* const* d_in, const int* in_sizes, int n_in,
                              void* d_out, int out_size, void* d_ws, size_t ws_size,
                              hipStream_t stream) {
  const float* in1 = (const float*)d_in[0];
  const float* in2 = (const float*)d_in[1];
  const float* w1  = (const float*)d_in[2];
  const float* w2  = (const float*)d_in[3];
  float* out = (float*)d_out;

  // workspace layout (bytes)
  char* ws = (char*)d_ws;
  bf16_t* in1b = (bf16_t*)(ws);                                   // 16 MiB
  bf16_t* in2b = (bf16_t*)(ws + (16u << 20));                     // 16 MiB
  bf16_t* w1t  = (bf16_t*)(ws + (32u << 20));                     // 256 KiB
  float*  lin  = (float*) (ws + (32u << 20) + (256u << 10));      // 512 KiB
  bf16_t* T    = (bf16_t*)(ws + (33u << 20));                     // 32 MiB

  prep_kernel<<<16448, 256, 0, stream>>>(in1, in2, w1, w2, in1b, in2b, w1t, lin);
  gemm1_kernel<<<dim3(4, 256), 256, 0, stream>>>(in1b, w1t, T);
  gemm2_kernel<<<dim3(8, 8, NB), 256, 0, stream>>>(T, in2b, lin, out);
}

// Round 2
// 148.973 us; speedup vs baseline: 1.0485x; 1.0485x over previous
//
#include <hip/hip_runtime.h>
#include <hip/hip_bf16.h>
#include <cstdint>
#include <cstddef>

// ---------------------------------------------------------------------------
// Biaffine: out[b,x,y,o] = sum_ij in1[b,x,i] w1[i,o,j] in2[b,y,j]
//                        + in1[b,x,:]@w2[:D] + in2[b,y,:]@w2[D:2D] + w2[2D]
// B=32 S=1024 D=256 O=2.
//   prep : cast inputs to bf16, lin terms, w1 transpose
//   gemm1: T[bx, oj] = in1b @ w1t^T        (persistent-A, B streamed)
//   gemm2: out[b,x,y,o] = T . in2b + lin   (persistent-A panel, B streamed,
//                                           2-phase dbuf, write-bound)
// ---------------------------------------------------------------------------

typedef __bf16 bf16_t;
typedef __bf16 bf16x4 __attribute__((ext_vector_type(4)));
typedef __bf16 bf16x8 __attribute__((ext_vector_type(8)));
typedef float  f32x4  __attribute__((ext_vector_type(4)));

#define NB   32
#define NS   1024
#define ND   256
#define NM   (NB * NS)
#define NN1  512

__device__ __forceinline__ void gload_lds16(const void* g, void* l) {
  __builtin_amdgcn_global_load_lds(
      (__attribute__((address_space(1))) void*)g,
      (__attribute__((address_space(3))) void*)l, 16, 0, 0);
}

// ---------------------------------------------------------------------------
// prep (unchanged from R1)
// ---------------------------------------------------------------------------
__global__ __launch_bounds__(256) void prep_kernel(
    const float* __restrict__ in1, const float* __restrict__ in2,
    const float* __restrict__ w1,  const float* __restrict__ w2,
    bf16_t* __restrict__ in1b, bf16_t* __restrict__ in2b,
    bf16_t* __restrict__ w1t,  float* __restrict__ lin)
{
  int bid = blockIdx.x;
  if (bid < 16384) {
    int wave = threadIdx.x >> 6;
    int lane = threadIdx.x & 63;
    int r  = bid * 4 + wave;
    int is2 = (r >= NM) ? 1 : 0;
    int lr = r & (NM - 1);
    const float* src = is2 ? in2 : in1;
    bf16_t*      dst = is2 ? in2b : in1b;

    float4 v = *(const float4*)(src + (size_t)lr * ND + lane * 4);
    bf16x4 h;
    h[0] = (bf16_t)v.x; h[1] = (bf16_t)v.y; h[2] = (bf16_t)v.z; h[3] = (bf16_t)v.w;
    *(bf16x4*)(dst + (size_t)lr * ND + lane * 4) = h;

    int dbase = is2 * ND + lane * 4;
    float a0 = v.x * w2[(dbase + 0) * 2 + 0] + v.y * w2[(dbase + 1) * 2 + 0]
             + v.z * w2[(dbase + 2) * 2 + 0] + v.w * w2[(dbase + 3) * 2 + 0];
    float a1 = v.x * w2[(dbase + 0) * 2 + 1] + v.y * w2[(dbase + 1) * 2 + 1]
             + v.z * w2[(dbase + 2) * 2 + 1] + v.w * w2[(dbase + 3) * 2 + 1];
    #pragma unroll
    for (int off = 32; off > 0; off >>= 1) {
      a0 += __shfl_down(a0, off, 64);
      a1 += __shfl_down(a1, off, 64);
    }
    if (lane == 0) {
      if (is2) { a0 += w2[2 * ND * 2 + 0]; a1 += w2[2 * ND * 2 + 1]; }
      lin[r * 2 + 0] = a0;
      lin[r * 2 + 1] = a1;
    }
  } else {
    int wb = bid - 16384;
    int t  = threadIdx.x;
    #pragma unroll
    for (int e = 0; e < 8; ++e) {
      int q  = wb * 2048 + e * 256 + t;
      int oj = q >> 8;
      int i  = q & 255;
      w1t[q] = (bf16_t)w1[i * NN1 + oj];
    }
  }
}

// ---------------------------------------------------------------------------
// gemm1: T[m,oj] = in1b[m,:] . w1t[oj,:]   M=32768 N=512 K=256
// persistent-A: A-tile 128x256 (64 KB, swizzled) resident; w1t streamed in
// [128 rows x 32 k] chunks (8 KB, dbuf). 32 steps = 4 n-tiles x 8 k-chunks.
// ---------------------------------------------------------------------------
__global__ __launch_bounds__(256, 1) void gemm1_kernel(
    const bf16_t* __restrict__ A, const bf16_t* __restrict__ Bt,
    bf16_t* __restrict__ T)
{
  __shared__ __align__(16) bf16_t Ap[128 * 256];     // 64 KB, slot^=(row&7)
  __shared__ __align__(16) bf16_t Bc[2][128 * 32];   // 2 x 8 KB, slot^=(row&3)

  int m0 = blockIdx.x * 128;
  int t = threadIdx.x, lane = t & 63, wid = t >> 6;
  int wm = (wid >> 1) * 64, wn = (wid & 1) * 64;

  // stage swizzled A-panel: 4096 16B units, 32 slots/row
  #pragma unroll
  for (int i = 0; i < 16; ++i) {
    int unit = i * 256 + t;
    int row = unit >> 5;
    int c   = unit & 31;
    int cs  = c ^ (row & 7);
    gload_lds16(A + (size_t)(m0 + row) * ND + cs * 8, (char*)Ap + unit * 16);
  }
  // stage B chunk 0 (nt=0, j0=0)
  #pragma unroll
  for (int i = 0; i < 2; ++i) {
    int unit = i * 256 + t;
    int row = unit >> 2, c = unit & 3, cs = c ^ (row & 3);
    gload_lds16(Bt + (size_t)row * ND + cs * 8, (char*)Bc[0] + unit * 16);
  }
  __syncthreads();

  f32x4 acc[4][4] = {};

  for (int s = 0; s < 32; ++s) {
    if (s + 1 < 32) {
      int nt = (s + 1) >> 3, j0 = ((s + 1) & 7) * 32;
      bf16_t* dst = (bf16_t*)Bc[(s + 1) & 1];
      #pragma unroll
      for (int i = 0; i < 2; ++i) {
        int unit = i * 256 + t;
        int row = unit >> 2, c = unit & 3, cs = c ^ (row & 3);
        gload_lds16(Bt + (size_t)(nt * 128 + row) * ND + j0 + cs * 8,
                    (char*)dst + unit * 16);
      }
    }
    const bf16_t* Bcur = Bc[s & 1];
    bf16x8 bfr[4];
    #pragma unroll
    for (int ni = 0; ni < 4; ++ni) {
      int r = wn + ni * 16 + (lane & 15);
      int cp = (lane >> 4) ^ (r & 3);
      bfr[ni] = *(const bf16x8*)&Bcur[r * 32 + cp * 8];
    }
    #pragma unroll
    for (int mi = 0; mi < 4; ++mi) {
      int r = wm + mi * 16 + (lane & 15);
      int cl = (s & 7) * 4 + (lane >> 4);
      int cp = cl ^ (r & 7);
      bf16x8 af = *(const bf16x8*)&Ap[r * 256 + cp * 8];
      #pragma unroll
      for (int ni = 0; ni < 4; ++ni)
        acc[mi][ni] = __builtin_amdgcn_mfma_f32_16x16x32_bf16(
            af, bfr[ni], acc[mi][ni], 0, 0, 0);
    }
    if ((s & 7) == 7) {
      int nt = s >> 3;
      #pragma unroll
      for (int mi = 0; mi < 4; ++mi) {
        int row = m0 + wm + mi * 16 + ((lane >> 4) << 2);
        #pragma unroll
        for (int ni = 0; ni < 4; ++ni) {
          int col = nt * 128 + wn + ni * 16 + (lane & 15);
          #pragma unroll
          for (int r_ = 0; r_ < 4; ++r_)
            T[(size_t)(row + r_) * NN1 + col] = (bf16_t)acc[mi][ni][r_];
          acc[mi][ni] = (f32x4){0.f, 0.f, 0.f, 0.f};
        }
      }
    }
    __syncthreads();
  }
}

// ---------------------------------------------------------------------------
// gemm2: per (b, x-tile): A-panel = T[x0:x0+128, 0:512] (128 KB, swizzled)
// resident; loop 8 y-tiles streaming in2b in [128 x 32] chunks (8 KB, dbuf).
// 64 steps, 1 barrier/step. Epilogue every 8th step (float2 stores + lin).
// ---------------------------------------------------------------------------
__global__ __launch_bounds__(256, 1) void gemm2_kernel(
    const bf16_t* __restrict__ Tm, const bf16_t* __restrict__ in2b,
    const float* __restrict__ lin, float* __restrict__ out)
{
  __shared__ __align__(16) bf16_t Ap[128 * 512];     // 128 KB, slot^=(row&7)
  __shared__ __align__(16) bf16_t Bc[2][128 * 32];   // 2 x 8 KB, slot^=(row&3)

  int blk = blockIdx.x;                // 0..255
  int b   = blk >> 3;
  int x0  = (blk & 7) * 128;
  const bf16_t* Tb = Tm   + (size_t)b * NS * NN1;
  const bf16_t* Ib = in2b + (size_t)b * NS * ND;

  int t = threadIdx.x, lane = t & 63, wid = t >> 6;
  int wm = (wid >> 1) * 64, wn = (wid & 1) * 64;

  // stage swizzled A-panel: 8192 16B units, 64 slots/row
  #pragma unroll
  for (int i = 0; i < 32; ++i) {
    int unit = i * 256 + t;
    int row = unit >> 6;
    int c   = unit & 63;
    int cs  = c ^ (row & 7);
    gload_lds16(Tb + (size_t)(x0 + row) * NN1 + cs * 8, (char*)Ap + unit * 16);
  }
  // stage B chunk 0 (yi=0, j0=0)
  #pragma unroll
  for (int i = 0; i < 2; ++i) {
    int unit = i * 256 + t;
    int row = unit >> 2, c = unit & 3, cs = c ^ (row & 3);
    gload_lds16(Ib + (size_t)row * ND + cs * 8, (char*)Bc[0] + unit * 16);
  }
  __syncthreads();

  f32x4 acc0[4][4] = {};
  f32x4 acc1[4][4] = {};
  float2* outb = (float2*)(out + (size_t)b * NS * NS * 2);
  const float2* l1p = (const float2*)(lin + (size_t)b * NS * 2);
  const float2* l2p = (const float2*)(lin + (size_t)(NM + b * NS) * 2);

  for (int s = 0; s < 64; ++s) {
    if (s + 1 < 64) {
      int yi = (s + 1) >> 3, j0 = ((s + 1) & 7) * 32;
      bf16_t* dst = (bf16_t*)Bc[(s + 1) & 1];
      #pragma unroll
      for (int i = 0; i < 2; ++i) {
        int unit = i * 256 + t;
        int row = unit >> 2, c = unit & 3, cs = c ^ (row & 3);
        gload_lds16(Ib + (size_t)(yi * 128 + row) * ND + j0 + cs * 8,
                    (char*)dst + unit * 16);
      }
    }
    const bf16_t* Bcur = Bc[s & 1];
    bf16x8 bfr[4];
    #pragma unroll
    for (int ni = 0; ni < 4; ++ni) {
      int r = wn + ni * 16 + (lane & 15);
      int cp = (lane >> 4) ^ (r & 3);
      bfr[ni] = *(const bf16x8*)&Bcur[r * 32 + cp * 8];
    }
    #pragma unroll
    for (int mi = 0; mi < 4; ++mi) {
      int r = wm + mi * 16 + (lane & 15);
      int cl = (s & 7) * 4 + (lane >> 4);          // o=0 slot (0..31)
      int cp0 = cl ^ (r & 7);
      bf16x8 af0 = *(const bf16x8*)&Ap[r * 512 + cp0 * 8];
      #pragma unroll
      for (int ni = 0; ni < 4; ++ni)
        acc0[mi][ni] = __builtin_amdgcn_mfma_f32_16x16x32_bf16(
            af0, bfr[ni], acc0[mi][ni], 0, 0, 0);
      int cp1 = (cl + 32) ^ (r & 7);               // o=1 slot (32..63)
      bf16x8 af1 = *(const bf16x8*)&Ap[r * 512 + cp1 * 8];
      #pragma unroll
      for (int ni = 0; ni < 4; ++ni)
        acc1[mi][ni] = __builtin_amdgcn_mfma_f32_16x16x32_bf16(
            af1, bfr[ni], acc1[mi][ni], 0, 0, 0);
    }
    if ((s & 7) == 7) {
      int y0 = (s >> 3) * 128;
      #pragma unroll
      for (int mi = 0; mi < 4; ++mi) {
        int rb = x0 + wm + mi * 16 + ((lane >> 4) << 2);
        float2 l1[4];
        #pragma unroll
        for (int r_ = 0; r_ < 4; ++r_) l1[r_] = l1p[rb + r_];
        #pragma unroll
        for (int ni = 0; ni < 4; ++ni) {
          int col = y0 + wn + ni * 16 + (lane & 15);
          float2 l2 = l2p[col];
          #pragma unroll
          for (int r_ = 0; r_ < 4; ++r_) {
            float2 v;
            v.x = acc0[mi][ni][r_] + l1[r_].x + l2.x;
            v.y = acc1[mi][ni][r_] + l1[r_].y + l2.y;
            outb[(size_t)(rb + r_) * NS + col] = v;
          }
          acc0[mi][ni] = (f32x4){0.f, 0.f, 0.f, 0.f};
          acc1[mi][ni] = (f32x4){0.f, 0.f, 0.f, 0.f};
        }
      }
    }
    __syncthreads();
  }
}

// ---------------------------------------------------------------------------
extern "C" void kernel_launch(void* const* d_in, const int* in_sizes, int n_in,
                              void* d_out, int out_size, void* d_ws, size_t ws_size,
                              hipStream_t stream) {
  const float* in1 = (const float*)d_in[0];
  const float* in2 = (const float*)d_in[1];
  const float* w1  = (const float*)d_in[2];
  const float* w2  = (const float*)d_in[3];
  float* out = (float*)d_out;

  char* ws = (char*)d_ws;
  bf16_t* in1b = (bf16_t*)(ws);                                   // 16 MiB
  bf16_t* in2b = (bf16_t*)(ws + (16u << 20));                     // 16 MiB
  bf16_t* w1t  = (bf16_t*)(ws + (32u << 20));                     // 256 KiB
  float*  lin  = (float*) (ws + (32u << 20) + (256u << 10));      // 512 KiB
  bf16_t* T    = (bf16_t*)(ws + (33u << 20));                     // 32 MiB

  prep_kernel<<<16448, 256, 0, stream>>>(in1, in2, w1, w2, in1b, in2b, w1t, lin);
  gemm1_kernel<<<256, 256, 0, stream>>>(in1b, w1t, T);
  gemm2_kernel<<<256, 256, 0, stream>>>(T, in2b, lin, out);
}

// Round 3
// 133.852 us; speedup vs baseline: 1.1670x; 1.1130x over previous
//
#include <hip/hip_runtime.h>
#include <hip/hip_bf16.h>
#include <cstdint>
#include <cstddef>

// ---------------------------------------------------------------------------
// Biaffine: out[b,x,y,o] = sum_ij in1[b,x,i] w1[i,o,j] in2[b,y,j] + lin terms
// B=32 S=1024 D=256 O=2.
//   prep : cast inputs to bf16, lin terms, w1 transpose
//   gemm1: T[bx, oj] = in1b @ w1t^T      (BM=64, 3 blocks/CU)
//   gemm2: out = T . in2b + lin          (BM=64 BN=64 BK=32, 72KB LDS,
//                                         2 blocks/CU for store/compute overlap,
//                                         XCD-swizzled for in2b L2 reuse)
// ---------------------------------------------------------------------------

typedef __bf16 bf16_t;
typedef __bf16 bf16x4 __attribute__((ext_vector_type(4)));
typedef __bf16 bf16x8 __attribute__((ext_vector_type(8)));
typedef float  f32x4  __attribute__((ext_vector_type(4)));

#define NB   32
#define NS   1024
#define ND   256
#define NM   (NB * NS)
#define NN1  512

__device__ __forceinline__ void gload_lds16(const void* g, void* l) {
  __builtin_amdgcn_global_load_lds(
      (__attribute__((address_space(1))) void*)g,
      (__attribute__((address_space(3))) void*)l, 16, 0, 0);
}

// ---------------------------------------------------------------------------
// prep (unchanged)
// ---------------------------------------------------------------------------
__global__ __launch_bounds__(256) void prep_kernel(
    const float* __restrict__ in1, const float* __restrict__ in2,
    const float* __restrict__ w1,  const float* __restrict__ w2,
    bf16_t* __restrict__ in1b, bf16_t* __restrict__ in2b,
    bf16_t* __restrict__ w1t,  float* __restrict__ lin)
{
  int bid = blockIdx.x;
  if (bid < 16384) {
    int wave = threadIdx.x >> 6;
    int lane = threadIdx.x & 63;
    int r  = bid * 4 + wave;
    int is2 = (r >= NM) ? 1 : 0;
    int lr = r & (NM - 1);
    const float* src = is2 ? in2 : in1;
    bf16_t*      dst = is2 ? in2b : in1b;

    float4 v = *(const float4*)(src + (size_t)lr * ND + lane * 4);
    bf16x4 h;
    h[0] = (bf16_t)v.x; h[1] = (bf16_t)v.y; h[2] = (bf16_t)v.z; h[3] = (bf16_t)v.w;
    *(bf16x4*)(dst + (size_t)lr * ND + lane * 4) = h;

    int dbase = is2 * ND + lane * 4;
    float a0 = v.x * w2[(dbase + 0) * 2 + 0] + v.y * w2[(dbase + 1) * 2 + 0]
             + v.z * w2[(dbase + 2) * 2 + 0] + v.w * w2[(dbase + 3) * 2 + 0];
    float a1 = v.x * w2[(dbase + 0) * 2 + 1] + v.y * w2[(dbase + 1) * 2 + 1]
             + v.z * w2[(dbase + 2) * 2 + 1] + v.w * w2[(dbase + 3) * 2 + 1];
    #pragma unroll
    for (int off = 32; off > 0; off >>= 1) {
      a0 += __shfl_down(a0, off, 64);
      a1 += __shfl_down(a1, off, 64);
    }
    if (lane == 0) {
      if (is2) { a0 += w2[2 * ND * 2 + 0]; a1 += w2[2 * ND * 2 + 1]; }
      lin[r * 2 + 0] = a0;
      lin[r * 2 + 1] = a1;
    }
  } else {
    int wb = bid - 16384;
    int t  = threadIdx.x;
    #pragma unroll
    for (int e = 0; e < 8; ++e) {
      int q  = wb * 2048 + e * 256 + t;
      int oj = q >> 8;
      int i  = q & 255;
      w1t[q] = (bf16_t)w1[i * NN1 + oj];
    }
  }
}

// ---------------------------------------------------------------------------
// gemm1: T[m,oj] = in1b[m,:] . w1t[oj,:]   M=32768 N=512 K=256
// BM=64: A-panel 64x256 (32 KB) resident; w1t streamed [128 x 32k] (2x8 KB).
// 32 steps = 4 n-tiles x 8 k-chunks. 48 KB LDS -> 3 blocks/CU.
// ---------------------------------------------------------------------------
__global__ __launch_bounds__(256, 3) void gemm1_kernel(
    const bf16_t* __restrict__ A, const bf16_t* __restrict__ Bt,
    bf16_t* __restrict__ T)
{
  __shared__ __align__(16) bf16_t Ap[64 * 256];      // 32 KB, slot^=(row&7)
  __shared__ __align__(16) bf16_t Bc[2][128 * 32];   // 2 x 8 KB, slot^=(row&3)

  int m0 = blockIdx.x * 64;
  int t = threadIdx.x, lane = t & 63, wid = t >> 6;
  int wm = (wid >> 1) * 32, wn = (wid & 1) * 64;

  // stage swizzled A-panel: 2048 16B units, 32 slots/row
  #pragma unroll
  for (int i = 0; i < 8; ++i) {
    int unit = i * 256 + t;
    int row = unit >> 5;
    int c   = unit & 31;
    int cs  = c ^ (row & 7);
    gload_lds16(A + (size_t)(m0 + row) * ND + cs * 8, (char*)Ap + unit * 16);
  }
  // B chunk 0
  #pragma unroll
  for (int i = 0; i < 2; ++i) {
    int unit = i * 256 + t;
    int row = unit >> 2, c = unit & 3, cs = c ^ (row & 3);
    gload_lds16(Bt + (size_t)row * ND + cs * 8, (char*)Bc[0] + unit * 16);
  }
  __syncthreads();

  f32x4 acc[2][4] = {};

  for (int s = 0; s < 32; ++s) {
    if (s + 1 < 32) {
      int nt = (s + 1) >> 3, j0 = ((s + 1) & 7) * 32;
      bf16_t* dst = (bf16_t*)Bc[(s + 1) & 1];
      #pragma unroll
      for (int i = 0; i < 2; ++i) {
        int unit = i * 256 + t;
        int row = unit >> 2, c = unit & 3, cs = c ^ (row & 3);
        gload_lds16(Bt + (size_t)(nt * 128 + row) * ND + j0 + cs * 8,
                    (char*)dst + unit * 16);
      }
    }
    const bf16_t* Bcur = Bc[s & 1];
    bf16x8 bfr[4];
    #pragma unroll
    for (int ni = 0; ni < 4; ++ni) {
      int r = wn + ni * 16 + (lane & 15);
      int cp = (lane >> 4) ^ (r & 3);
      bfr[ni] = *(const bf16x8*)&Bcur[r * 32 + cp * 8];
    }
    #pragma unroll
    for (int mi = 0; mi < 2; ++mi) {
      int r = wm + mi * 16 + (lane & 15);
      int cl = (s & 7) * 4 + (lane >> 4);
      int cp = cl ^ (r & 7);
      bf16x8 af = *(const bf16x8*)&Ap[r * 256 + cp * 8];
      #pragma unroll
      for (int ni = 0; ni < 4; ++ni)
        acc[mi][ni] = __builtin_amdgcn_mfma_f32_16x16x32_bf16(
            af, bfr[ni], acc[mi][ni], 0, 0, 0);
    }
    if ((s & 7) == 7) {
      int nt = s >> 3;
      #pragma unroll
      for (int mi = 0; mi < 2; ++mi) {
        int row = m0 + wm + mi * 16 + ((lane >> 4) << 2);
        #pragma unroll
        for (int ni = 0; ni < 4; ++ni) {
          int col = nt * 128 + wn + ni * 16 + (lane & 15);
          #pragma unroll
          for (int r_ = 0; r_ < 4; ++r_)
            T[(size_t)(row + r_) * NN1 + col] = (bf16_t)acc[mi][ni][r_];
          acc[mi][ni] = (f32x4){0.f, 0.f, 0.f, 0.f};
        }
      }
    }
    __syncthreads();
  }
}

// ---------------------------------------------------------------------------
// gemm2: per (b, 64-row x-tile): A-panel = T[x0:x0+64, 0:512] (64 KB) resident;
// stream in2b in [64 rows x 32 k] chunks (2x4 KB dbuf). 128 steps =
// 16 y-tiles x 8 k-chunks. 72 KB LDS -> 2 blocks/CU (store/compute overlap).
// ---------------------------------------------------------------------------
__global__ __launch_bounds__(256, 2) void gemm2_kernel(
    const bf16_t* __restrict__ Tm, const bf16_t* __restrict__ in2b,
    const float* __restrict__ lin, float* __restrict__ out)
{
  __shared__ __align__(16) bf16_t Ap[64 * 512];      // 64 KB, slot^=(row&7)
  __shared__ __align__(16) bf16_t Bc[2][64 * 32];    // 2 x 4 KB, slot^=(row&3)

  // XCD-aware bijective swizzle: 512 blocks, 64 per XCD -> batches 4k..4k+3
  int blk = (blockIdx.x & 7) * 64 + (blockIdx.x >> 3);
  int b   = blk >> 4;
  int x0  = (blk & 15) * 64;
  const bf16_t* Tb = Tm   + (size_t)b * NS * NN1;
  const bf16_t* Ib = in2b + (size_t)b * NS * ND;

  int t = threadIdx.x, lane = t & 63, wid = t >> 6;
  int wm = (wid >> 1) * 32, wn = (wid & 1) * 32;

  // stage swizzled A-panel: 4096 16B units, 64 slots/row
  #pragma unroll
  for (int i = 0; i < 16; ++i) {
    int unit = i * 256 + t;
    int row = unit >> 6;
    int c   = unit & 63;
    int cs  = c ^ (row & 7);
    gload_lds16(Tb + (size_t)(x0 + row) * NN1 + cs * 8, (char*)Ap + unit * 16);
  }
  // B chunk 0: 256 units (64 rows x 4 slots), 1 per thread
  {
    int row = t >> 2, c = t & 3, cs = c ^ (row & 3);
    gload_lds16(Ib + (size_t)row * ND + cs * 8, (char*)Bc[0] + t * 16);
  }
  __syncthreads();

  f32x4 acc0[2][2] = {};
  f32x4 acc1[2][2] = {};
  float2* outb = (float2*)(out + (size_t)b * NS * NS * 2);
  const float2* l1p = (const float2*)(lin + (size_t)b * NS * 2);
  const float2* l2p = (const float2*)(lin + (size_t)(NM + b * NS) * 2);

  for (int s = 0; s < 128; ++s) {
    if (s + 1 < 128) {
      int yi = (s + 1) >> 3, j0 = ((s + 1) & 7) * 32;
      bf16_t* dst = (bf16_t*)Bc[(s + 1) & 1];
      int row = t >> 2, c = t & 3, cs = c ^ (row & 3);
      gload_lds16(Ib + (size_t)(yi * 64 + row) * ND + j0 + cs * 8,
                  (char*)dst + t * 16);
    }
    const bf16_t* Bcur = Bc[s & 1];
    bf16x8 bfr[2];
    #pragma unroll
    for (int ni = 0; ni < 2; ++ni) {
      int r = wn + ni * 16 + (lane & 15);
      int cp = (lane >> 4) ^ (r & 3);
      bfr[ni] = *(const bf16x8*)&Bcur[r * 32 + cp * 8];
    }
    #pragma unroll
    for (int mi = 0; mi < 2; ++mi) {
      int r = wm + mi * 16 + (lane & 15);
      int cl = (s & 7) * 4 + (lane >> 4);          // o=0 slot
      int cp0 = cl ^ (r & 7);
      bf16x8 af0 = *(const bf16x8*)&Ap[r * 512 + cp0 * 8];
      #pragma unroll
      for (int ni = 0; ni < 2; ++ni)
        acc0[mi][ni] = __builtin_amdgcn_mfma_f32_16x16x32_bf16(
            af0, bfr[ni], acc0[mi][ni], 0, 0, 0);
      int cp1 = (cl + 32) ^ (r & 7);               // o=1 slot
      bf16x8 af1 = *(const bf16x8*)&Ap[r * 512 + cp1 * 8];
      #pragma unroll
      for (int ni = 0; ni < 2; ++ni)
        acc1[mi][ni] = __builtin_amdgcn_mfma_f32_16x16x32_bf16(
            af1, bfr[ni], acc1[mi][ni], 0, 0, 0);
    }
    if ((s & 7) == 7) {
      int y0 = (s >> 3) * 64;
      #pragma unroll
      for (int mi = 0; mi < 2; ++mi) {
        int rb = x0 + wm + mi * 16 + ((lane >> 4) << 2);
        float2 l1[4];
        #pragma unroll
        for (int r_ = 0; r_ < 4; ++r_) l1[r_] = l1p[rb + r_];
        #pragma unroll
        for (int ni = 0; ni < 2; ++ni) {
          int col = y0 + wn + ni * 16 + (lane & 15);
          float2 l2 = l2p[col];
          #pragma unroll
          for (int r_ = 0; r_ < 4; ++r_) {
            float2 v;
            v.x = acc0[mi][ni][r_] + l1[r_].x + l2.x;
            v.y = acc1[mi][ni][r_] + l1[r_].y + l2.y;
            outb[(size_t)(rb + r_) * NS + col] = v;
          }
          acc0[mi][ni] = (f32x4){0.f, 0.f, 0.f, 0.f};
          acc1[mi][ni] = (f32x4){0.f, 0.f, 0.f, 0.f};
        }
      }
    }
    __syncthreads();
  }
}

// ---------------------------------------------------------------------------
extern "C" void kernel_launch(void* const* d_in, const int* in_sizes, int n_in,
                              void* d_out, int out_size, void* d_ws, size_t ws_size,
                              hipStream_t stream) {
  const float* in1 = (const float*)d_in[0];
  const float* in2 = (const float*)d_in[1];
  const float* w1  = (const float*)d_in[2];
  const float* w2  = (const float*)d_in[3];
  float* out = (float*)d_out;

  char* ws = (char*)d_ws;
  bf16_t* in1b = (bf16_t*)(ws);                                   // 16 MiB
  bf16_t* in2b = (bf16_t*)(ws + (16u << 20));                     // 16 MiB
  bf16_t* w1t  = (bf16_t*)(ws + (32u << 20));                     // 256 KiB
  float*  lin  = (float*) (ws + (32u << 20) + (256u << 10));      // 512 KiB
  bf16_t* T    = (bf16_t*)(ws + (33u << 20));                     // 32 MiB

  prep_kernel<<<16448, 256, 0, stream>>>(in1, in2, w1, w2, in1b, in2b, w1t, lin);
  gemm1_kernel<<<512, 256, 0, stream>>>(in1b, w1t, T);
  gemm2_kernel<<<512, 256, 0, stream>>>(T, in2b, lin, out);
}

// Round 4
// 116.869 us; speedup vs baseline: 1.3366x; 1.1453x over previous
//
#include <hip/hip_runtime.h>
#include <hip/hip_bf16.h>
#include <cstdint>
#include <cstddef>

// ---------------------------------------------------------------------------
// Biaffine: out[b,x,y,o] = sum_ij in1[b,x,i] w1[i,o,j] in2[b,y,j] + lin terms
// B=32 S=1024 D=256 O=2.
//   prep : cast inputs to bf16, lin terms, w1 transpose
//   gemm1: T[bx, oj] = in1b @ w1t^T      (16x16x32, BM=64)
//   gemm2: out = T . in2b + lin          (32x32x16, A in REGISTERS (128 VGPR),
//                                         B streamed 128y x 64k dbuf, LDS
//                                         union 64KB, 2 blocks/CU, XCD swizzle)
// ---------------------------------------------------------------------------

typedef __bf16 bf16_t;
typedef __bf16 bf16x4 __attribute__((ext_vector_type(4)));
typedef __bf16 bf16x8 __attribute__((ext_vector_type(8)));
typedef float  f32x4  __attribute__((ext_vector_type(4)));
typedef float  f32x16 __attribute__((ext_vector_type(16)));

#define NB   32
#define NS   1024
#define ND   256
#define NM   (NB * NS)
#define NN1  512

__device__ __forceinline__ void gload_lds16(const void* g, void* l) {
  __builtin_amdgcn_global_load_lds(
      (__attribute__((address_space(1))) void*)g,
      (__attribute__((address_space(3))) void*)l, 16, 0, 0);
}

// ---------------------------------------------------------------------------
// prep (unchanged)
// ---------------------------------------------------------------------------
__global__ __launch_bounds__(256) void prep_kernel(
    const float* __restrict__ in1, const float* __restrict__ in2,
    const float* __restrict__ w1,  const float* __restrict__ w2,
    bf16_t* __restrict__ in1b, bf16_t* __restrict__ in2b,
    bf16_t* __restrict__ w1t,  float* __restrict__ lin)
{
  int bid = blockIdx.x;
  if (bid < 16384) {
    int wave = threadIdx.x >> 6;
    int lane = threadIdx.x & 63;
    int r  = bid * 4 + wave;
    int is2 = (r >= NM) ? 1 : 0;
    int lr = r & (NM - 1);
    const float* src = is2 ? in2 : in1;
    bf16_t*      dst = is2 ? in2b : in1b;

    float4 v = *(const float4*)(src + (size_t)lr * ND + lane * 4);
    bf16x4 h;
    h[0] = (bf16_t)v.x; h[1] = (bf16_t)v.y; h[2] = (bf16_t)v.z; h[3] = (bf16_t)v.w;
    *(bf16x4*)(dst + (size_t)lr * ND + lane * 4) = h;

    int dbase = is2 * ND + lane * 4;
    float a0 = v.x * w2[(dbase + 0) * 2 + 0] + v.y * w2[(dbase + 1) * 2 + 0]
             + v.z * w2[(dbase + 2) * 2 + 0] + v.w * w2[(dbase + 3) * 2 + 0];
    float a1 = v.x * w2[(dbase + 0) * 2 + 1] + v.y * w2[(dbase + 1) * 2 + 1]
             + v.z * w2[(dbase + 2) * 2 + 1] + v.w * w2[(dbase + 3) * 2 + 1];
    #pragma unroll
    for (int off = 32; off > 0; off >>= 1) {
      a0 += __shfl_down(a0, off, 64);
      a1 += __shfl_down(a1, off, 64);
    }
    if (lane == 0) {
      if (is2) { a0 += w2[2 * ND * 2 + 0]; a1 += w2[2 * ND * 2 + 1]; }
      lin[r * 2 + 0] = a0;
      lin[r * 2 + 1] = a1;
    }
  } else {
    int wb = bid - 16384;
    int t  = threadIdx.x;
    #pragma unroll
    for (int e = 0; e < 8; ++e) {
      int q  = wb * 2048 + e * 256 + t;
      int oj = q >> 8;
      int i  = q & 255;
      w1t[q] = (bf16_t)w1[i * NN1 + oj];
    }
  }
}

// ---------------------------------------------------------------------------
// gemm1 (unchanged from R3): T[m,oj] = in1b[m,:] . w1t[oj,:]
// ---------------------------------------------------------------------------
__global__ __launch_bounds__(256, 3) void gemm1_kernel(
    const bf16_t* __restrict__ A, const bf16_t* __restrict__ Bt,
    bf16_t* __restrict__ T)
{
  __shared__ __align__(16) bf16_t Ap[64 * 256];
  __shared__ __align__(16) bf16_t Bc[2][128 * 32];

  int m0 = blockIdx.x * 64;
  int t = threadIdx.x, lane = t & 63, wid = t >> 6;
  int wm = (wid >> 1) * 32, wn = (wid & 1) * 64;

  #pragma unroll
  for (int i = 0; i < 8; ++i) {
    int unit = i * 256 + t;
    int row = unit >> 5;
    int c   = unit & 31;
    int cs  = c ^ (row & 7);
    gload_lds16(A + (size_t)(m0 + row) * ND + cs * 8, (char*)Ap + unit * 16);
  }
  #pragma unroll
  for (int i = 0; i < 2; ++i) {
    int unit = i * 256 + t;
    int row = unit >> 2, c = unit & 3, cs = c ^ (row & 3);
    gload_lds16(Bt + (size_t)row * ND + cs * 8, (char*)Bc[0] + unit * 16);
  }
  __syncthreads();

  f32x4 acc[2][4] = {};

  for (int s = 0; s < 32; ++s) {
    if (s + 1 < 32) {
      int nt = (s + 1) >> 3, j0 = ((s + 1) & 7) * 32;
      bf16_t* dst = (bf16_t*)Bc[(s + 1) & 1];
      #pragma unroll
      for (int i = 0; i < 2; ++i) {
        int unit = i * 256 + t;
        int row = unit >> 2, c = unit & 3, cs = c ^ (row & 3);
        gload_lds16(Bt + (size_t)(nt * 128 + row) * ND + j0 + cs * 8,
                    (char*)dst + unit * 16);
      }
    }
    const bf16_t* Bcur = Bc[s & 1];
    bf16x8 bfr[4];
    #pragma unroll
    for (int ni = 0; ni < 4; ++ni) {
      int r = wn + ni * 16 + (lane & 15);
      int cp = (lane >> 4) ^ (r & 3);
      bfr[ni] = *(const bf16x8*)&Bcur[r * 32 + cp * 8];
    }
    #pragma unroll
    for (int mi = 0; mi < 2; ++mi) {
      int r = wm + mi * 16 + (lane & 15);
      int cl = (s & 7) * 4 + (lane >> 4);
      int cp = cl ^ (r & 7);
      bf16x8 af = *(const bf16x8*)&Ap[r * 256 + cp * 8];
      #pragma unroll
      for (int ni = 0; ni < 4; ++ni)
        acc[mi][ni] = __builtin_amdgcn_mfma_f32_16x16x32_bf16(
            af, bfr[ni], acc[mi][ni], 0, 0, 0);
    }
    if ((s & 7) == 7) {
      int nt = s >> 3;
      #pragma unroll
      for (int mi = 0; mi < 2; ++mi) {
        int row = m0 + wm + mi * 16 + ((lane >> 4) << 2);
        #pragma unroll
        for (int ni = 0; ni < 4; ++ni) {
          int col = nt * 128 + wn + ni * 16 + (lane & 15);
          #pragma unroll
          for (int r_ = 0; r_ < 4; ++r_)
            T[(size_t)(row + r_) * NN1 + col] = (bf16_t)acc[mi][ni][r_];
          acc[mi][ni] = (f32x4){0.f, 0.f, 0.f, 0.f};
        }
      }
    }
    __syncthreads();
  }
}

// ---------------------------------------------------------------------------
// gemm2: per (b, 64-row x-tile). A = T[x0:x0+64, 0:512] held in REGISTERS
// (per wave: 32 rows x K256 x o2 = 32 bf16x8 frags = 128 VGPR).
// B = in2b streamed [128y x 64k] chunks (16 KB, dbuf in LDS union with the
// one-shot A staging panel). 32 steps = 8 y-tiles x 4 k-chunks.
// MFMA 32x32x16. 64 KB LDS -> 2 blocks/CU. Waves: 2x (32 x-rows) x 2y (64 y).
// ---------------------------------------------------------------------------
__global__ __launch_bounds__(256, 2) void gemm2_kernel(
    const bf16_t* __restrict__ Tm, const bf16_t* __restrict__ in2b,
    const float* __restrict__ lin, float* __restrict__ out)
{
  __shared__ __align__(16) char smem[65536];
  bf16_t* Ap = (bf16_t*)smem;                 // 64x512 bf16, one-shot staging
  bf16_t* Bbuf[2] = { (bf16_t*)smem, (bf16_t*)(smem + 16384) };  // after prefill

  // XCD-aware bijective swizzle: 512 blocks, 64/XCD -> 4 batches per XCD
  int blk = (blockIdx.x & 7) * 64 + (blockIdx.x >> 3);
  int b   = blk >> 4;
  int x0  = (blk & 15) * 64;
  const bf16_t* Tb = Tm   + (size_t)b * NS * NN1;
  const bf16_t* Ib = in2b + (size_t)b * NS * ND;

  int t = threadIdx.x, lane = t & 63, wid = t >> 6;
  int wx = (wid >> 1) * 32;        // x-slot: 0 or 32
  int wy = (wid & 1) * 64;         // y-slot within 128-chunk: 0 or 64
  int l31 = lane & 31, lhi = lane >> 5;

  // ---- stage A-panel (swizzled): 4096 16B units, 64 slots/row ----
  #pragma unroll
  for (int i = 0; i < 16; ++i) {
    int unit = i * 256 + t;
    int row = unit >> 6;
    int c   = unit & 63;
    int cs  = c ^ (row & 7);
    gload_lds16(Tb + (size_t)(x0 + row) * NN1 + cs * 8, (char*)Ap + unit * 16);
  }
  __syncthreads();

  // ---- prefill A-frags into registers: af[o][ks], 32x bf16x8 = 128 VGPR ----
  // 32x32x16 A layout (analog of verified 16x16x32): row = lane&31,
  // k = (lane>>5)*8 + e. Frag (o,ks) covers k = ks*16 .. ks*16+15 of column
  // block o*256.. ; LDS slot (8 bf16) logical = o*32 + ks*2 + lhi, ^ row&7.
  bf16x8 af[2][16];
  {
    int row = wx + l31;
    #pragma unroll
    for (int o = 0; o < 2; ++o)
      #pragma unroll
      for (int ks = 0; ks < 16; ++ks) {
        int ls = o * 32 + ks * 2 + lhi;
        int sm = ls ^ (row & 7);
        af[o][ks] = *(const bf16x8*)&Ap[(row * 64 + sm) * 8];
      }
  }
  __syncthreads();   // everyone done reading Ap before B overwrites it

  // ---- stage B chunk 0 (yi=0,kc=0): 1024 units, 8 slots/row, ^row&7 ----
  #pragma unroll
  for (int i = 0; i < 4; ++i) {
    int u = i * 256 + t;
    int row = u >> 3, sm = u & 7;
    int cs = sm ^ (row & 7);
    gload_lds16(Ib + (size_t)row * ND + cs * 8, (char*)Bbuf[0] + u * 16);
  }
  __syncthreads();

  f32x16 acc[2][2] = {};   // [ni][o]
  float2* outb = (float2*)(out + (size_t)b * NS * NS * 2);
  const float2* l1p = (const float2*)(lin + (size_t)b * NS * 2);
  const float2* l2p = (const float2*)(lin + (size_t)(NM + b * NS) * 2);

  for (int yi = 0; yi < 8; ++yi) {
    #pragma unroll
    for (int kc = 0; kc < 4; ++kc) {
      // prefetch next chunk (parity (kc+1)&1 is compile-time)
      if (yi < 7 || kc < 3) {
        int c1 = yi * 4 + kc + 1;
        int yn = c1 >> 2, kn = (c1 & 3) * 64;
        char* dst = (char*)Bbuf[(kc + 1) & 1];
        #pragma unroll
        for (int i = 0; i < 4; ++i) {
          int u = i * 256 + t;
          int row = u >> 3, sm = u & 7;
          int cs = sm ^ (row & 7);
          gload_lds16(Ib + (size_t)(yn * 128 + row) * ND + kn + cs * 8,
                      dst + u * 16);
        }
      }
      const bf16_t* Bp = Bbuf[kc & 1];
      #pragma unroll
      for (int ni = 0; ni < 2; ++ni) {
        int row = wy + ni * 32 + l31;
        #pragma unroll
        for (int k2 = 0; k2 < 4; ++k2) {
          int ls = k2 * 2 + lhi;
          int sm = ls ^ (row & 7);
          bf16x8 bf = *(const bf16x8*)&Bp[(row * 8 + sm) * 8];
          acc[ni][0] = __builtin_amdgcn_mfma_f32_32x32x16_bf16(
              af[0][kc * 4 + k2], bf, acc[ni][0], 0, 0, 0);
          acc[ni][1] = __builtin_amdgcn_mfma_f32_32x32x16_bf16(
              af[1][kc * 4 + k2], bf, acc[ni][1], 0, 0, 0);
        }
      }
      if (kc == 3) {
        // epilogue for this y-tile of 128
        int y0 = yi * 128;
        float2 l2[2];
        #pragma unroll
        for (int ni = 0; ni < 2; ++ni) l2[ni] = l2p[y0 + wy + ni * 32 + l31];
        int xr = x0 + wx + 4 * lhi;
        #pragma unroll
        for (int r = 0; r < 16; ++r) {
          int row = xr + (r & 3) + 8 * (r >> 2);
          float2 l1 = l1p[row];
          #pragma unroll
          for (int ni = 0; ni < 2; ++ni) {
            int col = y0 + wy + ni * 32 + l31;
            float2 v;
            v.x = acc[ni][0][r] + l1.x + l2[ni].x;
            v.y = acc[ni][1][r] + l1.y + l2[ni].y;
            outb[(size_t)row * NS + col] = v;
          }
        }
        acc[0][0] = (f32x16)(0.f); acc[0][1] = (f32x16)(0.f);
        acc[1][0] = (f32x16)(0.f); acc[1][1] = (f32x16)(0.f);
      }
      __syncthreads();
    }
  }
}

// ---------------------------------------------------------------------------
extern "C" void kernel_launch(void* const* d_in, const int* in_sizes, int n_in,
                              void* d_out, int out_size, void* d_ws, size_t ws_size,
                              hipStream_t stream) {
  const float* in1 = (const float*)d_in[0];
  const float* in2 = (const float*)d_in[1];
  const float* w1  = (const float*)d_in[2];
  const float* w2  = (const float*)d_in[3];
  float* out = (float*)d_out;

  char* ws = (char*)d_ws;
  bf16_t* in1b = (bf16_t*)(ws);                                   // 16 MiB
  bf16_t* in2b = (bf16_t*)(ws + (16u << 20));                     // 16 MiB
  bf16_t* w1t  = (bf16_t*)(ws + (32u << 20));                     // 256 KiB
  float*  lin  = (float*) (ws + (32u << 20) + (256u << 10));      // 512 KiB
  bf16_t* T    = (bf16_t*)(ws + (33u << 20));                     // 32 MiB

  prep_kernel<<<16448, 256, 0, stream>>>(in1, in2, w1, w2, in1b, in2b, w1t, lin);
  gemm1_kernel<<<512, 256, 0, stream>>>(in1b, w1t, T);
  gemm2_kernel<<<512, 256, 0, stream>>>(T, in2b, lin, out);
}